// Round 4
// baseline (142.044 us; speedup 1.0000x reference)
//
#include <hip/hip_runtime.h>
#include <hip/hip_bf16.h>
#include <cstdint>
#include <type_traits>

#define DM 1024
#define HEADS 16
#define DH 64
#define SEQ 2048
#define BATCH 2

typedef __attribute__((ext_vector_type(8))) short bf16x8;
typedef __attribute__((ext_vector_type(4))) float f32x4;
typedef __attribute__((ext_vector_type(16))) float f32x16;
typedef __attribute__((ext_vector_type(2))) unsigned int u32x2;
typedef __attribute__((ext_vector_type(4))) unsigned int u32x4;

#define SCALE2 0.18033688011112042f   /* (1/8)*log2(e) */

static __device__ __forceinline__ unsigned short f2bf(float f) {
    unsigned u = __builtin_bit_cast(unsigned, f);
    u = u + 0x7fffu + ((u >> 16) & 1u);
    return (unsigned short)(u >> 16);
}

// ---------------- fused cast fp32 -> bf16, all 6 tensors in one launch ----------------
__global__ __launch_bounds__(256) void cast_all_k(
    const float* __restrict__ q, const float* __restrict__ kv,
    const float* __restrict__ wq, const float* __restrict__ wk,
    const float* __restrict__ wv, const float* __restrict__ wo,
    unsigned short* __restrict__ qb, unsigned short* __restrict__ kvb,
    unsigned short* __restrict__ wqb, unsigned short* __restrict__ wkb,
    unsigned short* __restrict__ wvb, unsigned short* __restrict__ wob)
{
    int blk = blockIdx.x;
    const float* s; unsigned short* d; int base;
    if (blk < 2048)      { s = q;  d = qb;  base = 0; }
    else if (blk < 4096) { s = kv; d = kvb; base = 2048; }
    else if (blk < 4608) { s = wq; d = wqb; base = 4096; }
    else if (blk < 5120) { s = wk; d = wkb; base = 4608; }
    else if (blk < 5632) { s = wv; d = wvb; base = 5120; }
    else                 { s = wo; d = wob; base = 5632; }
    int i = ((blk - base) * 256 + threadIdx.x) * 8;
    float4 a = *(const float4*)(s + i);
    float4 b2 = *(const float4*)(s + i + 4);
    ushort4 o0, o1;
    o0.x = f2bf(a.x);  o0.y = f2bf(a.y);  o0.z = f2bf(a.z);  o0.w = f2bf(a.w);
    o1.x = f2bf(b2.x); o1.y = f2bf(b2.y); o1.z = f2bf(b2.z); o1.w = f2bf(b2.w);
    *(ushort4*)(d + i) = o0;
    *(ushort4*)(d + i + 4) = o1;
}

// ---------------- NT GEMM: C[m][n] = sum_k A[m][k]*B[n][k] + bias[n] ----------------
template<int EPI>
__global__ __launch_bounds__(256) void gemm_nt(
    const unsigned short* __restrict__ A,
    const unsigned short* __restrict__ Bw,
    const float* __restrict__ biasA,
    const float* __restrict__ biasB,
    void* __restrict__ out0,
    void* __restrict__ out1,
    int M, int N, int K)
{
    constexpr int BK = 64;
    __shared__ alignas(16) unsigned short As[64 * BK];
    __shared__ alignas(16) unsigned short Bs[128 * BK];

    const int t = threadIdx.x;
    const int lane = t & 63;
    const int w = t >> 6;
    const int wn = w * 32;
    const int lr = lane & 15, lg = lane >> 4;
    const int m0 = blockIdx.x * 64, n0 = blockIdx.y * 128;

    f32x4 acc[4][2] = {};

    const int srow = t >> 3;
    const int schunk = t & 7;

    for (int kt = 0; kt < K; kt += BK) {
#pragma unroll
        for (int c = 0; c < 2; c++) {
            int row = srow + c * 32;
            int gc = schunk ^ (row & 7);
            __builtin_amdgcn_global_load_lds(
                (const __attribute__((address_space(1))) unsigned int*)(A + (size_t)(m0 + row) * K + kt + gc * 8),
                (__attribute__((address_space(3))) unsigned int*)(&As[row * BK + schunk * 8]), 16, 0, 0);
        }
#pragma unroll
        for (int c = 0; c < 4; c++) {
            int row = srow + c * 32;
            int gc = schunk ^ (row & 7);
            __builtin_amdgcn_global_load_lds(
                (const __attribute__((address_space(1))) unsigned int*)(Bw + (size_t)(n0 + row) * K + kt + gc * 8),
                (__attribute__((address_space(3))) unsigned int*)(&Bs[row * BK + schunk * 8]), 16, 0, 0);
        }
        __syncthreads();
#pragma unroll
        for (int kk = 0; kk < 2; kk++) {
            bf16x8 af[4], bfr[2];
#pragma unroll
            for (int i = 0; i < 4; i++)
                af[i] = *(const bf16x8*)(&As[(i * 16 + lr) * BK + (((kk * 4 + lg) ^ (lr & 7))) * 8]);
#pragma unroll
            for (int jj = 0; jj < 2; jj++)
                bfr[jj] = *(const bf16x8*)(&Bs[(wn + jj * 16 + lr) * BK + (((kk * 4 + lg) ^ (lr & 7))) * 8]);
#pragma unroll
            for (int i = 0; i < 4; i++)
#pragma unroll
                for (int jj = 0; jj < 2; jj++)
                    acc[i][jj] = __builtin_amdgcn_mfma_f32_16x16x32_bf16(af[i], bfr[jj], acc[i][jj], 0, 0, 0);
        }
        __syncthreads();
    }

    if constexpr (EPI == 0) {
        unsigned short* C = (unsigned short*)out0;
#pragma unroll
        for (int i = 0; i < 4; i++) {
            int rbase = m0 + i * 16 + lg * 4;
#pragma unroll
            for (int jj = 0; jj < 2; jj++) {
                int col = n0 + wn + jj * 16 + lr;
                float bv = biasA[col];
#pragma unroll
                for (int r = 0; r < 4; r++)
                    C[(size_t)(rbase + r) * 1024 + col] = f2bf((acc[i][jj][r] + bv) * SCALE2);
            }
        }
    } else if constexpr (EPI == 1) {
        if (n0 < 1024) {
            unsigned short* C = (unsigned short*)out0;
#pragma unroll
            for (int i = 0; i < 4; i++) {
                int rbase = m0 + i * 16 + lg * 4;
#pragma unroll
                for (int jj = 0; jj < 2; jj++) {
                    int col = n0 + wn + jj * 16 + lr;
                    float bv = biasA[col];
#pragma unroll
                    for (int r = 0; r < 4; r++)
                        C[(size_t)(rbase + r) * 1024 + col] = f2bf(acc[i][jj][r] + bv);
                }
            }
        } else {
            unsigned short* C = (unsigned short*)out1;
            int bidx = m0 >> 11;
#pragma unroll
            for (int i = 0; i < 4; i++) {
                int s0 = (m0 & 2047) + i * 16 + lg * 4;
#pragma unroll
                for (int jj = 0; jj < 2; jj++) {
                    int nv = n0 - 1024 + wn + jj * 16 + lr;
                    float bv = biasB[nv];
                    int hh = nv >> 6, dd = nv & 63;
                    ushort4 st;
                    st.x = f2bf(acc[i][jj][0] + bv);
                    st.y = f2bf(acc[i][jj][1] + bv);
                    st.z = f2bf(acc[i][jj][2] + bv);
                    st.w = f2bf(acc[i][jj][3] + bv);
                    *(ushort4*)(C + ((size_t)((bidx * HEADS + hh) * DH + dd)) * SEQ + s0) = st;
                }
            }
        }
    } else {
        float* C = (float*)out0;
#pragma unroll
        for (int i = 0; i < 4; i++) {
            int rbase = m0 + i * 16 + lg * 4;
#pragma unroll
            for (int jj = 0; jj < 2; jj++) {
                int col = n0 + wn + jj * 16 + lr;
                float bv = biasA[col];
#pragma unroll
                for (int r = 0; r < 4; r++)
                    C[(size_t)(rbase + r) * 1024 + col] = acc[i][jj][r] + bv;
            }
        }
    }
}

// ---------------- causal flash attention: KV-split, 2 waves per q-tile ----------------
// Qp (pre-scaled), Kp: bf16 [B][S][1024]; Vt: bf16 [B][H][64][S]; Ctx: bf16 [B][S][1024]
// grid (16, H, B), 8 waves. Waves (2p,2p+1) share a q-tile, processing strided KV halves
// (kb tile index == half mod 2); merged via one LDS exchange at the end.
__global__ __launch_bounds__(512, 4) void attn_k(
    const unsigned short* __restrict__ Qp,
    const unsigned short* __restrict__ Kp,
    const unsigned short* __restrict__ Vt,
    unsigned short* __restrict__ Ctx)
{
    __shared__ float oBuf[8][64][18];
    __shared__ float2 mlBuf[8][64];

    const int lane = threadIdx.x & 63;
    const int w = threadIdx.x >> 6;
    const int j = blockIdx.x;
    const int h = blockIdx.y, b = blockIdx.z;

    int qt;
    if (w < 2)      qt = 63 - 2 * j;
    else if (w < 4) qt = 62 - 2 * j;
    else if (w < 6) qt = 2 * j;
    else            qt = 2 * j + 1;
    const int half = w & 1;
    const int q0 = qt * 32;
    const int lq = lane & 31;
    const int hi = lane >> 5;
    const int qq = q0 + lq;
    const int nt = qt + 1;
    const int n = (nt + 1 - half) >> 1;   // this wave's iteration count
    constexpr float THR = 11.5f;

    bf16x8 Qf[4];
    {
        const unsigned short* qb = Qp + (size_t)(b * SEQ + qq) * DM + h * DH + hi * 8;
#pragma unroll
        for (int d = 0; d < 4; d++) Qf[d] = *(const bf16x8*)(qb + d * 16);
    }

    const unsigned short* kbase = Kp + ((size_t)(b * SEQ + lq)) * DM + h * DH + hi * 8;
    const unsigned short* vbase = Vt + ((size_t)((b * HEADS + h) * DH) + lq) * SEQ + hi * 8;

    f32x16 o0 = {}, o1 = {};
    float m_run = -1e30f, l_run = 0.f;
    bf16x8 Kc[4];

    {   // prologue K load (first tile of this half; harmless if n == 0)
        const unsigned short* kp = kbase + (size_t)(half * 32) * DM;
#pragma unroll
        for (int d = 0; d < 4; d++) Kc[d] = *(const bf16x8*)(kp + d * 16);
    }

    const int qmh0 = qq - 4 * hi;

    auto body = [&](int kbt, auto PF) {
        constexpr bool pf = PF.value;
        const int kb = kbt * 32;

        // V for current tile (issued first; consumed ~QK+softmax later)
        bf16x8 Vc[4];
        {
            const unsigned short* vp = vbase + kb;
#pragma unroll
            for (int s = 0; s < 2; s++)
#pragma unroll
                for (int dt = 0; dt < 2; dt++)
                    Vc[s * 2 + dt] = *(const bf16x8*)(vp + (size_t)dt * 32 * SEQ + s * 16);
        }
        bf16x8 Kn[4];
        if constexpr (pf) {
            const unsigned short* kp = kbase + (size_t)(kb + 64) * DM;
#pragma unroll
            for (int d = 0; d < 4; d++) Kn[d] = *(const bf16x8*)(kp + d * 16);
        }

        f32x16 sa = {};
#pragma unroll
        for (int d = 0; d < 4; d++)
            sa = __builtin_amdgcn_mfma_f32_32x32x16_bf16(Kc[d], Qf[d], sa, 0, 0, 0);

        const int qmh = qmh0 - kb;
#pragma unroll
        for (int r = 0; r < 16; r++) {
            int kvl = (r & 3) + 8 * (r >> 2);
            sa[r] = (kvl <= qmh) ? sa[r] : -1e30f;
        }
        float mx[8];
#pragma unroll
        for (int r = 0; r < 8; r++) mx[r] = fmaxf(sa[2 * r], sa[2 * r + 1]);
#pragma unroll
        for (int r = 0; r < 4; r++) mx[r] = fmaxf(mx[r], mx[r + 4]);
        mx[0] = fmaxf(mx[0], mx[2]);
        mx[1] = fmaxf(mx[1], mx[3]);
        float mloc = fmaxf(mx[0], mx[1]);
        mloc = fmaxf(mloc, __shfl_xor(mloc, 32));

        if (!__all(mloc - m_run <= THR)) {
            float m_new = fmaxf(m_run, mloc);
            float sf = __builtin_amdgcn_exp2f(m_run - m_new);
            l_run *= sf;
#pragma unroll
            for (int r = 0; r < 16; r++) { o0[r] *= sf; o1[r] *= sf; }
            m_run = m_new;
        }

        float ps = 0.f;
        unsigned c[8];
#pragma unroll
        for (int i = 0; i < 8; i++) {
            float p0 = __builtin_amdgcn_exp2f(sa[2 * i] - m_run);
            float p1 = __builtin_amdgcn_exp2f(sa[2 * i + 1] - m_run);
            ps += p0 + p1;
            unsigned pk;
            asm("v_cvt_pk_bf16_f32 %0, %1, %2" : "=v"(pk) : "v"(p0), "v"(p1));
            c[i] = pk;
        }
        ps += __shfl_xor(ps, 32);
        l_run += ps;

        u32x2 r02 = __builtin_amdgcn_permlane32_swap(c[0], c[2], false, false);
        u32x2 r13 = __builtin_amdgcn_permlane32_swap(c[1], c[3], false, false);
        u32x2 r46 = __builtin_amdgcn_permlane32_swap(c[4], c[6], false, false);
        u32x2 r57 = __builtin_amdgcn_permlane32_swap(c[5], c[7], false, false);
        u32x4 w0 = {r02.x, r13.x, r02.y, r13.y};
        u32x4 w1 = {r46.x, r57.x, r46.y, r57.y};
        bf16x8 Pb0 = __builtin_bit_cast(bf16x8, w0);
        bf16x8 Pb1 = __builtin_bit_cast(bf16x8, w1);

        o0 = __builtin_amdgcn_mfma_f32_32x32x16_bf16(Vc[0], Pb0, o0, 0, 0, 0);
        o1 = __builtin_amdgcn_mfma_f32_32x32x16_bf16(Vc[1], Pb0, o1, 0, 0, 0);
        o0 = __builtin_amdgcn_mfma_f32_32x32x16_bf16(Vc[2], Pb1, o0, 0, 0, 0);
        o1 = __builtin_amdgcn_mfma_f32_32x32x16_bf16(Vc[3], Pb1, o1, 0, 0, 0);

        if constexpr (pf) {
#pragma unroll
            for (int d = 0; d < 4; d++) Kc[d] = Kn[d];
        }
    };

    for (int i = 0; i + 1 < n; i++)
        body(2 * i + half, std::true_type{});
    if (n > 0)
        body(2 * (n - 1) + half, std::false_type{});

    // ---- pair merge: wave 2p holds half0, 2p+1 holds half1 of tile qt ----
    {   // write the o-half the partner will store, plus (m, l)
        float* ob = &oBuf[w][lane][0];
        const f32x16& oX = (w & 1) ? o0 : o1;
#pragma unroll
        for (int e = 0; e < 8; e++)
            *(float2*)(ob + 2 * e) = make_float2(oX[2 * e], oX[2 * e + 1]);
        mlBuf[w][lane] = make_float2(m_run, l_run);
    }
    __syncthreads();

    float2 mlO = mlBuf[w ^ 1][lane];
    const float* obO = &oBuf[w ^ 1][lane][0];
    float mM = fmaxf(m_run, mlO.x);
    float cS = __builtin_amdgcn_exp2f(m_run - mM);
    float cO = __builtin_amdgcn_exp2f(mlO.x - mM);
    float l = l_run * cS + mlO.y * cO;
    float inv = 1.0f / l;
    float fS = cS * inv, fO = cO * inv;

    const f32x16& oSelf = (w & 1) ? o1 : o0;   // even wave stores d 0..31, odd stores 32..63
    unsigned short* cb = Ctx + (size_t)(b * SEQ + qq) * DM + h * DH + hi * 4 + (w & 1) * 32;
#pragma unroll
    for (int g = 0; g < 4; g++) {
        ushort4 st;
        st.x = f2bf(oSelf[4 * g + 0] * fS + obO[4 * g + 0] * fO);
        st.y = f2bf(oSelf[4 * g + 1] * fS + obO[4 * g + 1] * fO);
        st.z = f2bf(oSelf[4 * g + 2] * fS + obO[4 * g + 2] * fO);
        st.w = f2bf(oSelf[4 * g + 3] * fS + obO[4 * g + 3] * fO);
        *(ushort4*)(cb + g * 8) = st;
    }
}

extern "C" void kernel_launch(void* const* d_in, const int* in_sizes, int n_in,
                              void* d_out, int out_size, void* d_ws, size_t ws_size,
                              hipStream_t stream)
{
    const float* query = (const float*)d_in[0];
    const float* keyv  = (const float*)d_in[1];
    const float* Wq = (const float*)d_in[2];
    const float* bq = (const float*)d_in[3];
    const float* Wk = (const float*)d_in[4];
    const float* bk = (const float*)d_in[5];
    const float* Wv = (const float*)d_in[6];
    const float* bv = (const float*)d_in[7];
    const float* Wo = (const float*)d_in[8];
    const float* bo = (const float*)d_in[9];
    float* out = (float*)d_out;

    const int M = BATCH * SEQ;
    char* ws = (char*)d_ws;
    size_t off = 0;
    auto alloc = [&](size_t elems) { unsigned short* p = (unsigned short*)(ws + off); off += elems * 2; return p; };
    unsigned short* qb  = alloc((size_t)M * DM);
    unsigned short* kvb = alloc((size_t)M * DM);
    unsigned short* wqb = alloc((size_t)DM * DM);
    unsigned short* wkb = alloc((size_t)DM * DM);   // wkb and wvb MUST stay adjacent (merged KV weights)
    unsigned short* wvb = alloc((size_t)DM * DM);
    unsigned short* wob = alloc((size_t)DM * DM);
    unsigned short* Qp  = alloc((size_t)M * DM);
    unsigned short* Kp  = alloc((size_t)M * DM);
    unsigned short* Vt  = alloc((size_t)M * DM);
    unsigned short* Ctx = alloc((size_t)M * DM);

    cast_all_k<<<6144, 256, 0, stream>>>(query, keyv, Wq, Wk, Wv, Wo,
                                         qb, kvb, wqb, wkb, wvb, wob);

    gemm_nt<0><<<dim3(M / 64, 8),  256, 0, stream>>>(qb,  wqb, bq, nullptr, Qp, nullptr, M, DM, DM);
    gemm_nt<1><<<dim3(M / 64, 16), 256, 0, stream>>>(kvb, wkb, bk, bv,      Kp, Vt,      M, 2 * DM, DM);

    attn_k<<<dim3(16, HEADS, BATCH), 512, 0, stream>>>(Qp, Kp, Vt, Ctx);

    gemm_nt<2><<<dim3(M / 64, 8),  256, 0, stream>>>(Ctx, wob, bo, nullptr, out, nullptr, M, DM, DM);
}

// Round 5
// 137.328 us; speedup vs baseline: 1.0343x; 1.0343x over previous
//
#include <hip/hip_runtime.h>
#include <hip/hip_bf16.h>
#include <cstdint>
#include <type_traits>

#define DM 1024
#define HEADS 16
#define DH 64
#define SEQ 2048
#define BATCH 2

typedef __attribute__((ext_vector_type(8))) short bf16x8;
typedef __attribute__((ext_vector_type(4))) float f32x4;
typedef __attribute__((ext_vector_type(16))) float f32x16;
typedef __attribute__((ext_vector_type(2))) unsigned int u32x2;
typedef __attribute__((ext_vector_type(4))) unsigned int u32x4;

#define SCALE2 0.18033688011112042f   /* (1/8)*log2(e) */

static __device__ __forceinline__ unsigned short f2bf(float f) {
    unsigned u = __builtin_bit_cast(unsigned, f);
    u = u + 0x7fffu + ((u >> 16) & 1u);
    return (unsigned short)(u >> 16);
}

// ---------------- fused cast fp32 -> bf16, all 6 tensors in one launch ----------------
__global__ __launch_bounds__(256) void cast_all_k(
    const float* __restrict__ q, const float* __restrict__ kv,
    const float* __restrict__ wq, const float* __restrict__ wk,
    const float* __restrict__ wv, const float* __restrict__ wo,
    unsigned short* __restrict__ qb, unsigned short* __restrict__ kvb,
    unsigned short* __restrict__ wqb, unsigned short* __restrict__ wkb,
    unsigned short* __restrict__ wvb, unsigned short* __restrict__ wob)
{
    int blk = blockIdx.x;
    const float* s; unsigned short* d; int base;
    if (blk < 2048)      { s = q;  d = qb;  base = 0; }
    else if (blk < 4096) { s = kv; d = kvb; base = 2048; }
    else if (blk < 4608) { s = wq; d = wqb; base = 4096; }
    else if (blk < 5120) { s = wk; d = wkb; base = 4608; }
    else if (blk < 5632) { s = wv; d = wvb; base = 5120; }
    else                 { s = wo; d = wob; base = 5632; }
    int i = ((blk - base) * 256 + threadIdx.x) * 8;
    float4 a = *(const float4*)(s + i);
    float4 b2 = *(const float4*)(s + i + 4);
    ushort4 o0, o1;
    o0.x = f2bf(a.x);  o0.y = f2bf(a.y);  o0.z = f2bf(a.z);  o0.w = f2bf(a.w);
    o1.x = f2bf(b2.x); o1.y = f2bf(b2.y); o1.z = f2bf(b2.z); o1.w = f2bf(b2.w);
    *(ushort4*)(d + i) = o0;
    *(ushort4*)(d + i + 4) = o1;
}

// ---------------- NT GEMM: C[m][n] = sum_k A[m][k]*B[n][k] + bias[n] ----------------
template<int EPI>
__global__ __launch_bounds__(256) void gemm_nt(
    const unsigned short* __restrict__ A,
    const unsigned short* __restrict__ Bw,
    const float* __restrict__ biasA,
    const float* __restrict__ biasB,
    void* __restrict__ out0,
    void* __restrict__ out1,
    int M, int N, int K)
{
    constexpr int BK = 64;
    __shared__ alignas(16) unsigned short As[64 * BK];
    __shared__ alignas(16) unsigned short Bs[128 * BK];

    const int t = threadIdx.x;
    const int lane = t & 63;
    const int w = t >> 6;
    const int wn = w * 32;
    const int lr = lane & 15, lg = lane >> 4;
    const int m0 = blockIdx.x * 64, n0 = blockIdx.y * 128;

    f32x4 acc[4][2] = {};

    const int srow = t >> 3;
    const int schunk = t & 7;

    for (int kt = 0; kt < K; kt += BK) {
#pragma unroll
        for (int c = 0; c < 2; c++) {
            int row = srow + c * 32;
            int gc = schunk ^ (row & 7);
            __builtin_amdgcn_global_load_lds(
                (const __attribute__((address_space(1))) unsigned int*)(A + (size_t)(m0 + row) * K + kt + gc * 8),
                (__attribute__((address_space(3))) unsigned int*)(&As[row * BK + schunk * 8]), 16, 0, 0);
        }
#pragma unroll
        for (int c = 0; c < 4; c++) {
            int row = srow + c * 32;
            int gc = schunk ^ (row & 7);
            __builtin_amdgcn_global_load_lds(
                (const __attribute__((address_space(1))) unsigned int*)(Bw + (size_t)(n0 + row) * K + kt + gc * 8),
                (__attribute__((address_space(3))) unsigned int*)(&Bs[row * BK + schunk * 8]), 16, 0, 0);
        }
        __syncthreads();
#pragma unroll
        for (int kk = 0; kk < 2; kk++) {
            bf16x8 af[4], bfr[2];
#pragma unroll
            for (int i = 0; i < 4; i++)
                af[i] = *(const bf16x8*)(&As[(i * 16 + lr) * BK + (((kk * 4 + lg) ^ (lr & 7))) * 8]);
#pragma unroll
            for (int jj = 0; jj < 2; jj++)
                bfr[jj] = *(const bf16x8*)(&Bs[(wn + jj * 16 + lr) * BK + (((kk * 4 + lg) ^ (lr & 7))) * 8]);
#pragma unroll
            for (int i = 0; i < 4; i++)
#pragma unroll
                for (int jj = 0; jj < 2; jj++)
                    acc[i][jj] = __builtin_amdgcn_mfma_f32_16x16x32_bf16(af[i], bfr[jj], acc[i][jj], 0, 0, 0);
        }
        __syncthreads();
    }

    if constexpr (EPI == 0) {
        unsigned short* C = (unsigned short*)out0;
#pragma unroll
        for (int i = 0; i < 4; i++) {
            int rbase = m0 + i * 16 + lg * 4;
#pragma unroll
            for (int jj = 0; jj < 2; jj++) {
                int col = n0 + wn + jj * 16 + lr;
                float bv = biasA[col];
#pragma unroll
                for (int r = 0; r < 4; r++)
                    C[(size_t)(rbase + r) * 1024 + col] = f2bf((acc[i][jj][r] + bv) * SCALE2);
            }
        }
    } else if constexpr (EPI == 1) {
        if (n0 < 1024) {
            unsigned short* C = (unsigned short*)out0;
#pragma unroll
            for (int i = 0; i < 4; i++) {
                int rbase = m0 + i * 16 + lg * 4;
#pragma unroll
                for (int jj = 0; jj < 2; jj++) {
                    int col = n0 + wn + jj * 16 + lr;
                    float bv = biasA[col];
#pragma unroll
                    for (int r = 0; r < 4; r++)
                        C[(size_t)(rbase + r) * 1024 + col] = f2bf(acc[i][jj][r] + bv);
                }
            }
        } else {
            unsigned short* C = (unsigned short*)out1;
            int bidx = m0 >> 11;
#pragma unroll
            for (int i = 0; i < 4; i++) {
                int s0 = (m0 & 2047) + i * 16 + lg * 4;
#pragma unroll
                for (int jj = 0; jj < 2; jj++) {
                    int nv = n0 - 1024 + wn + jj * 16 + lr;
                    float bv = biasB[nv];
                    int hh = nv >> 6, dd = nv & 63;
                    ushort4 st;
                    st.x = f2bf(acc[i][jj][0] + bv);
                    st.y = f2bf(acc[i][jj][1] + bv);
                    st.z = f2bf(acc[i][jj][2] + bv);
                    st.w = f2bf(acc[i][jj][3] + bv);
                    *(ushort4*)(C + ((size_t)((bidx * HEADS + hh) * DH + dd)) * SEQ + s0) = st;
                }
            }
        }
    } else {
        float* C = (float*)out0;
#pragma unroll
        for (int i = 0; i < 4; i++) {
            int rbase = m0 + i * 16 + lg * 4;
#pragma unroll
            for (int jj = 0; jj < 2; jj++) {
                int col = n0 + wn + jj * 16 + lr;
                float bv = biasA[col];
#pragma unroll
                for (int r = 0; r < 4; r++)
                    C[(size_t)(rbase + r) * 1024 + col] = acc[i][jj][r] + bv;
            }
        }
    }
}

// ---------------- causal flash attention: KV=64 per iteration ----------------
// Qp (pre-scaled), Kp: bf16 [B][S][1024]; Vt: bf16 [B][H][64][S]; Ctx: bf16 [B][S][1024]
// 1-D grid 256: x = bh + 32*j (same-bh blocks stride-32 => same XCD under rr dispatch).
// 8 waves; wave w owns q-tile qt = (w<4) ? 4j+w : 63-4j-(w&3); SIMD pair (w,w+4)
// totals ~33 KV64-iterations. K double-buffered; V issued at iter top (T14).
__global__ __launch_bounds__(512, 2) void attn_k(
    const unsigned short* __restrict__ Qp,
    const unsigned short* __restrict__ Kp,
    const unsigned short* __restrict__ Vt,
    unsigned short* __restrict__ Ctx)
{
    const int lane = threadIdx.x & 63;
    const int w = threadIdx.x >> 6;
    const int x = blockIdx.x;
    const int j = x >> 5;
    const int bh = x & 31;
    const int b = bh >> 4, h = bh & 15;
    const int qt = (w < 4) ? (j * 4 + w) : (63 - j * 4 - (w & 3));
    const int q0 = qt * 32;
    const int lq = lane & 31;
    const int hi = lane >> 5;
    const int qq = q0 + lq;
    const int nb = (qt >> 1) + 1;      // number of KV-64 blocks (last may be half, mask handles)
    constexpr float THR = 11.5f;

    bf16x8 Qf[4];
    {
        const unsigned short* qb = Qp + (size_t)(b * SEQ + qq) * DM + h * DH + hi * 8;
#pragma unroll
        for (int d = 0; d < 4; d++) Qf[d] = *(const bf16x8*)(qb + d * 16);
    }

    const unsigned short* kbase = Kp + ((size_t)(b * SEQ + lq)) * DM + h * DH + hi * 8;
    const unsigned short* vbase = Vt + ((size_t)((b * HEADS + h) * DH) + lq) * SEQ + hi * 8;

    f32x16 o0 = {}, o1 = {};
    float m_run = -1e30f, l_run = 0.f;
    bf16x8 KA[4], KB[4];               // current K block: rows kb+lq / kb+32+lq

    {   // prologue K load (block 0)
#pragma unroll
        for (int d = 0; d < 4; d++) {
            KA[d] = *(const bf16x8*)(kbase + d * 16);
            KB[d] = *(const bf16x8*)(kbase + (size_t)32 * DM + d * 16);
        }
    }

    const int qmh0 = qq - 4 * hi;

    auto body = [&](int ib, auto PF) {
        constexpr bool pf = PF.value;
        const int kb = ib * 64;

        // V for current block (8 frags), issued first, consumed after QK+softmax
        bf16x8 Vc[4][2];
        {
            const unsigned short* vp = vbase + kb;
#pragma unroll
            for (int s = 0; s < 4; s++)
#pragma unroll
                for (int dt = 0; dt < 2; dt++)
                    Vc[s][dt] = *(const bf16x8*)(vp + (size_t)dt * 32 * SEQ + s * 16);
        }
        bf16x8 KnA[4], KnB[4];
        if constexpr (pf) {
            const unsigned short* kp = kbase + (size_t)(kb + 64) * DM;
#pragma unroll
            for (int d = 0; d < 4; d++) {
                KnA[d] = *(const bf16x8*)(kp + d * 16);
                KnB[d] = *(const bf16x8*)(kp + (size_t)32 * DM + d * 16);
            }
        }

        f32x16 sa0 = {}, sa1 = {};
#pragma unroll
        for (int d = 0; d < 4; d++) {
            sa0 = __builtin_amdgcn_mfma_f32_32x32x16_bf16(KA[d], Qf[d], sa0, 0, 0, 0);
            sa1 = __builtin_amdgcn_mfma_f32_32x32x16_bf16(KB[d], Qf[d], sa1, 0, 0, 0);
        }

        // branchless causal mask: kv = kb + [0/32] + (r&3)+8*(r>>2)+4*hi <= qq
        const int qmh = qmh0 - kb;
#pragma unroll
        for (int r = 0; r < 16; r++) {
            int kvl = (r & 3) + 8 * (r >> 2);
            sa0[r] = (kvl <= qmh) ? sa0[r] : -1e30f;
            sa1[r] = (kvl + 32 <= qmh) ? sa1[r] : -1e30f;
        }
        // tree max over 32 values
        float mx[16];
#pragma unroll
        for (int r = 0; r < 16; r++) mx[r] = fmaxf(sa0[r], sa1[r]);
#pragma unroll
        for (int r = 0; r < 8; r++) mx[r] = fmaxf(mx[r], mx[r + 8]);
#pragma unroll
        for (int r = 0; r < 4; r++) mx[r] = fmaxf(mx[r], mx[r + 4]);
        mx[0] = fmaxf(mx[0], mx[2]);
        mx[1] = fmaxf(mx[1], mx[3]);
        float mloc = fmaxf(mx[0], mx[1]);
        mloc = fmaxf(mloc, __shfl_xor(mloc, 32));

        if (!__all(mloc - m_run <= THR)) {
            float m_new = fmaxf(m_run, mloc);
            float sf = __builtin_amdgcn_exp2f(m_run - m_new);
            l_run *= sf;
#pragma unroll
            for (int r = 0; r < 16; r++) { o0[r] *= sf; o1[r] *= sf; }
            m_run = m_new;
        }

        float p0v[16], p1v[16];
#pragma unroll
        for (int r = 0; r < 16; r++) {
            p0v[r] = __builtin_amdgcn_exp2f(sa0[r] - m_run);
            p1v[r] = __builtin_amdgcn_exp2f(sa1[r] - m_run);
        }
        // sum tree
        float s4[8];
#pragma unroll
        for (int r = 0; r < 8; r++) s4[r] = (p0v[r] + p0v[r + 8]) + (p1v[r] + p1v[r + 8]);
#pragma unroll
        for (int r = 0; r < 4; r++) s4[r] += s4[r + 4];
        float ps = (s4[0] + s4[1]) + (s4[2] + s4[3]);
        ps += __shfl_xor(ps, 32);
        l_run += ps;

        // pack P -> bf16 frags (verified mapping, per 32-half)
        unsigned c0[8], c1[8];
#pragma unroll
        for (int i = 0; i < 8; i++) {
            unsigned pk;
            asm("v_cvt_pk_bf16_f32 %0, %1, %2" : "=v"(pk) : "v"(p0v[2 * i]), "v"(p0v[2 * i + 1]));
            c0[i] = pk;
            asm("v_cvt_pk_bf16_f32 %0, %1, %2" : "=v"(pk) : "v"(p1v[2 * i]), "v"(p1v[2 * i + 1]));
            c1[i] = pk;
        }
        bf16x8 Pb[4];
        {
            u32x2 r02 = __builtin_amdgcn_permlane32_swap(c0[0], c0[2], false, false);
            u32x2 r13 = __builtin_amdgcn_permlane32_swap(c0[1], c0[3], false, false);
            u32x2 r46 = __builtin_amdgcn_permlane32_swap(c0[4], c0[6], false, false);
            u32x2 r57 = __builtin_amdgcn_permlane32_swap(c0[5], c0[7], false, false);
            u32x4 w0 = {r02.x, r13.x, r02.y, r13.y};
            u32x4 w1 = {r46.x, r57.x, r46.y, r57.y};
            Pb[0] = __builtin_bit_cast(bf16x8, w0);
            Pb[1] = __builtin_bit_cast(bf16x8, w1);
        }
        {
            u32x2 r02 = __builtin_amdgcn_permlane32_swap(c1[0], c1[2], false, false);
            u32x2 r13 = __builtin_amdgcn_permlane32_swap(c1[1], c1[3], false, false);
            u32x2 r46 = __builtin_amdgcn_permlane32_swap(c1[4], c1[6], false, false);
            u32x2 r57 = __builtin_amdgcn_permlane32_swap(c1[5], c1[7], false, false);
            u32x4 w0 = {r02.x, r13.x, r02.y, r13.y};
            u32x4 w1 = {r46.x, r57.x, r46.y, r57.y};
            Pb[2] = __builtin_bit_cast(bf16x8, w0);
            Pb[3] = __builtin_bit_cast(bf16x8, w1);
        }

#pragma unroll
        for (int s = 0; s < 4; s++) {
            o0 = __builtin_amdgcn_mfma_f32_32x32x16_bf16(Vc[s][0], Pb[s], o0, 0, 0, 0);
            o1 = __builtin_amdgcn_mfma_f32_32x32x16_bf16(Vc[s][1], Pb[s], o1, 0, 0, 0);
        }

        if constexpr (pf) {
#pragma unroll
            for (int d = 0; d < 4; d++) { KA[d] = KnA[d]; KB[d] = KnB[d]; }
        }
    };

    for (int ib = 0; ib + 1 < nb; ib++)
        body(ib, std::true_type{});
    body(nb - 1, std::false_type{});

    float inv = 1.0f / l_run;
    unsigned short* cb = Ctx + (size_t)(b * SEQ + qq) * DM + h * DH + hi * 4;
#pragma unroll
    for (int g = 0; g < 4; g++) {
        ushort4 s0, s1;
        s0.x = f2bf(o0[4 * g + 0] * inv); s0.y = f2bf(o0[4 * g + 1] * inv);
        s0.z = f2bf(o0[4 * g + 2] * inv); s0.w = f2bf(o0[4 * g + 3] * inv);
        s1.x = f2bf(o1[4 * g + 0] * inv); s1.y = f2bf(o1[4 * g + 1] * inv);
        s1.z = f2bf(o1[4 * g + 2] * inv); s1.w = f2bf(o1[4 * g + 3] * inv);
        *(ushort4*)(cb + g * 8) = s0;
        *(ushort4*)(cb + 32 + g * 8) = s1;
    }
}

extern "C" void kernel_launch(void* const* d_in, const int* in_sizes, int n_in,
                              void* d_out, int out_size, void* d_ws, size_t ws_size,
                              hipStream_t stream)
{
    const float* query = (const float*)d_in[0];
    const float* keyv  = (const float*)d_in[1];
    const float* Wq = (const float*)d_in[2];
    const float* bq = (const float*)d_in[3];
    const float* Wk = (const float*)d_in[4];
    const float* bk = (const float*)d_in[5];
    const float* Wv = (const float*)d_in[6];
    const float* bv = (const float*)d_in[7];
    const float* Wo = (const float*)d_in[8];
    const float* bo = (const float*)d_in[9];
    float* out = (float*)d_out;

    const int M = BATCH * SEQ;
    char* ws = (char*)d_ws;
    size_t off = 0;
    auto alloc = [&](size_t elems) { unsigned short* p = (unsigned short*)(ws + off); off += elems * 2; return p; };
    unsigned short* qb  = alloc((size_t)M * DM);
    unsigned short* kvb = alloc((size_t)M * DM);
    unsigned short* wqb = alloc((size_t)DM * DM);
    unsigned short* wkb = alloc((size_t)DM * DM);   // wkb and wvb MUST stay adjacent (merged KV weights)
    unsigned short* wvb = alloc((size_t)DM * DM);
    unsigned short* wob = alloc((size_t)DM * DM);
    unsigned short* Qp  = alloc((size_t)M * DM);
    unsigned short* Kp  = alloc((size_t)M * DM);
    unsigned short* Vt  = alloc((size_t)M * DM);
    unsigned short* Ctx = alloc((size_t)M * DM);

    cast_all_k<<<6144, 256, 0, stream>>>(query, keyv, Wq, Wk, Wv, Wo,
                                         qb, kvb, wqb, wkb, wvb, wob);

    gemm_nt<0><<<dim3(M / 64, 8),  256, 0, stream>>>(qb,  wqb, bq, nullptr, Qp, nullptr, M, DM, DM);
    gemm_nt<1><<<dim3(M / 64, 16), 256, 0, stream>>>(kvb, wkb, bk, bv,      Kp, Vt,      M, 2 * DM, DM);

    attn_k<<<dim3(256), 512, 0, stream>>>(Qp, Kp, Vt, Ctx);

    gemm_nt<2><<<dim3(M / 64, 8),  256, 0, stream>>>(Ctx, wob, bo, nullptr, out, nullptr, M, DM, DM);
}

// Round 7
// 121.082 us; speedup vs baseline: 1.1731x; 1.1342x over previous
//
#include <hip/hip_runtime.h>
#include <hip/hip_bf16.h>
#include <cstdint>
#include <type_traits>

#define DM 1024
#define HEADS 16
#define DH 64
#define SEQ 2048
#define BATCH 2

typedef __attribute__((ext_vector_type(8))) short bf16x8;
typedef __attribute__((ext_vector_type(4))) float f32x4;
typedef __attribute__((ext_vector_type(16))) float f32x16;
typedef __attribute__((ext_vector_type(2))) unsigned int u32x2;
typedef __attribute__((ext_vector_type(4))) unsigned int u32x4;

#define SCALE2 0.18033688011112042f   /* (1/8)*log2(e) */

static __device__ __forceinline__ unsigned short f2bf(float f) {
    unsigned u = __builtin_bit_cast(unsigned, f);
    u = u + 0x7fffu + ((u >> 16) & 1u);
    return (unsigned short)(u >> 16);
}

// ---------------- fused cast fp32 -> bf16, all 6 tensors in one launch ----------------
__global__ __launch_bounds__(256) void cast_all_k(
    const float* __restrict__ q, const float* __restrict__ kv,
    const float* __restrict__ wq, const float* __restrict__ wk,
    const float* __restrict__ wv, const float* __restrict__ wo,
    unsigned short* __restrict__ qb, unsigned short* __restrict__ kvb,
    unsigned short* __restrict__ wqb, unsigned short* __restrict__ wkb,
    unsigned short* __restrict__ wvb, unsigned short* __restrict__ wob)
{
    int blk = blockIdx.x;
    const float* s; unsigned short* d; int base;
    if (blk < 2048)      { s = q;  d = qb;  base = 0; }
    else if (blk < 4096) { s = kv; d = kvb; base = 2048; }
    else if (blk < 4608) { s = wq; d = wqb; base = 4096; }
    else if (blk < 5120) { s = wk; d = wkb; base = 4608; }
    else if (blk < 5632) { s = wv; d = wvb; base = 5120; }
    else                 { s = wo; d = wob; base = 5632; }
    int i = ((blk - base) * 256 + threadIdx.x) * 8;
    float4 a = *(const float4*)(s + i);
    float4 b2 = *(const float4*)(s + i + 4);
    ushort4 o0, o1;
    o0.x = f2bf(a.x);  o0.y = f2bf(a.y);  o0.z = f2bf(a.z);  o0.w = f2bf(a.w);
    o1.x = f2bf(b2.x); o1.y = f2bf(b2.y); o1.z = f2bf(b2.z); o1.w = f2bf(b2.w);
    *(ushort4*)(d + i) = o0;
    *(ushort4*)(d + i + 4) = o1;
}

// ---------------- NT GEMM: C[m][n] = sum_k A[m][k]*B[n][k] + bias[n] ----------------
template<int EPI>
__global__ __launch_bounds__(256) void gemm_nt(
    const unsigned short* __restrict__ A,
    const unsigned short* __restrict__ Bw,
    const float* __restrict__ biasA,
    const float* __restrict__ biasB,
    void* __restrict__ out0,
    void* __restrict__ out1,
    int M, int N, int K)
{
    constexpr int BK = 64;
    __shared__ alignas(16) unsigned short As[64 * BK];
    __shared__ alignas(16) unsigned short Bs[128 * BK];

    const int t = threadIdx.x;
    const int lane = t & 63;
    const int w = t >> 6;
    const int wn = w * 32;
    const int lr = lane & 15, lg = lane >> 4;
    const int m0 = blockIdx.x * 64, n0 = blockIdx.y * 128;

    f32x4 acc[4][2] = {};

    const int srow = t >> 3;
    const int schunk = t & 7;

    for (int kt = 0; kt < K; kt += BK) {
#pragma unroll
        for (int c = 0; c < 2; c++) {
            int row = srow + c * 32;
            int gc = schunk ^ (row & 7);
            __builtin_amdgcn_global_load_lds(
                (const __attribute__((address_space(1))) unsigned int*)(A + (size_t)(m0 + row) * K + kt + gc * 8),
                (__attribute__((address_space(3))) unsigned int*)(&As[row * BK + schunk * 8]), 16, 0, 0);
        }
#pragma unroll
        for (int c = 0; c < 4; c++) {
            int row = srow + c * 32;
            int gc = schunk ^ (row & 7);
            __builtin_amdgcn_global_load_lds(
                (const __attribute__((address_space(1))) unsigned int*)(Bw + (size_t)(n0 + row) * K + kt + gc * 8),
                (__attribute__((address_space(3))) unsigned int*)(&Bs[row * BK + schunk * 8]), 16, 0, 0);
        }
        __syncthreads();
#pragma unroll
        for (int kk = 0; kk < 2; kk++) {
            bf16x8 af[4], bfr[2];
#pragma unroll
            for (int i = 0; i < 4; i++)
                af[i] = *(const bf16x8*)(&As[(i * 16 + lr) * BK + (((kk * 4 + lg) ^ (lr & 7))) * 8]);
#pragma unroll
            for (int jj = 0; jj < 2; jj++)
                bfr[jj] = *(const bf16x8*)(&Bs[(wn + jj * 16 + lr) * BK + (((kk * 4 + lg) ^ (lr & 7))) * 8]);
#pragma unroll
            for (int i = 0; i < 4; i++)
#pragma unroll
                for (int jj = 0; jj < 2; jj++)
                    acc[i][jj] = __builtin_amdgcn_mfma_f32_16x16x32_bf16(af[i], bfr[jj], acc[i][jj], 0, 0, 0);
        }
        __syncthreads();
    }

    if constexpr (EPI == 0) {
        unsigned short* C = (unsigned short*)out0;
#pragma unroll
        for (int i = 0; i < 4; i++) {
            int rbase = m0 + i * 16 + lg * 4;
#pragma unroll
            for (int jj = 0; jj < 2; jj++) {
                int col = n0 + wn + jj * 16 + lr;
                float bv = biasA[col];
#pragma unroll
                for (int r = 0; r < 4; r++)
                    C[(size_t)(rbase + r) * 1024 + col] = f2bf((acc[i][jj][r] + bv) * SCALE2);
            }
        }
    } else if constexpr (EPI == 1) {
        if (n0 < 1024) {
            unsigned short* C = (unsigned short*)out0;
#pragma unroll
            for (int i = 0; i < 4; i++) {
                int rbase = m0 + i * 16 + lg * 4;
#pragma unroll
                for (int jj = 0; jj < 2; jj++) {
                    int col = n0 + wn + jj * 16 + lr;
                    float bv = biasA[col];
#pragma unroll
                    for (int r = 0; r < 4; r++)
                        C[(size_t)(rbase + r) * 1024 + col] = f2bf(acc[i][jj][r] + bv);
                }
            }
        } else {
            unsigned short* C = (unsigned short*)out1;
            int bidx = m0 >> 11;
#pragma unroll
            for (int i = 0; i < 4; i++) {
                int s0 = (m0 & 2047) + i * 16 + lg * 4;
#pragma unroll
                for (int jj = 0; jj < 2; jj++) {
                    int nv = n0 - 1024 + wn + jj * 16 + lr;
                    float bv = biasB[nv];
                    int hh = nv >> 6, dd = nv & 63;
                    ushort4 st;
                    st.x = f2bf(acc[i][jj][0] + bv);
                    st.y = f2bf(acc[i][jj][1] + bv);
                    st.z = f2bf(acc[i][jj][2] + bv);
                    st.w = f2bf(acc[i][jj][3] + bv);
                    *(ushort4*)(C + ((size_t)((bidx * HEADS + hh) * DH + dd)) * SEQ + s0) = st;
                }
            }
        }
    } else {
        float* C = (float*)out0;
#pragma unroll
        for (int i = 0; i < 4; i++) {
            int rbase = m0 + i * 16 + lg * 4;
#pragma unroll
            for (int jj = 0; jj < 2; jj++) {
                int col = n0 + wn + jj * 16 + lr;
                float bv = biasA[col];
#pragma unroll
                for (int r = 0; r < 4; r++)
                    C[(size_t)(rbase + r) * 1024 + col] = acc[i][jj][r] + bv;
            }
        }
    }
}

// ---------------- causal flash attention: block-cooperative LDS-staged K/V ----------------
// Qp (pre-scaled), Kp: bf16 [B][S][1024]; Vt: bf16 [B][H][64][S]; Ctx: bf16 [B][S][1024]
// Grid 512 = 32 bh x 16 q-chunks(128 rows); chunk permuted so paired blocks (x, x+256)
// have constant total work. Block: 4 waves, wave w owns q-tile q0+32w.
// Per KV-64 iter: stage K[64][128B] + Vt[64][128B] to LDS (double-buffered, XOR-swizzled
// via pre-swizzled global source per rule 21), 1 barrier, compute = R5 verified body.
__global__ __launch_bounds__(256, 2) void attn_k(
    const unsigned short* __restrict__ Qp,
    const unsigned short* __restrict__ Kp,
    const unsigned short* __restrict__ Vt,
    unsigned short* __restrict__ Ctx)
{
    __shared__ alignas(16) unsigned char ldsb[2 * 16384];   // [buf][K 8KB | V 8KB]

    const int lane = threadIdx.x & 63;
    const int w = threadIdx.x >> 6;          // 0..3
    const int x = blockIdx.x;
    const int bh = x & 31;
    const int i16 = x >> 5;                  // 0..15
    const int c = (i16 < 8) ? (2 * i16) : (31 - 2 * i16);   // pair-sum = 15
    const int b = bh >> 4, h = bh & 15;
    const int q0 = c * 128;
    const int lq = lane & 31;
    const int hi = lane >> 5;
    const int qq = q0 + w * 32 + lq;
    const int nb = 2 * c + 2;                              // block iterations
    const int my_nb = (q0 + 32 * w + 95) >> 6;             // this wave's compute iterations
    constexpr float THR = 11.5f;

    // Q fragments
    bf16x8 Qf[4];
    {
        const unsigned short* qb = Qp + (size_t)(b * SEQ + qq) * DM + h * DH + hi * 8;
#pragma unroll
        for (int d = 0; d < 4; d++) Qf[d] = *(const bf16x8*)(qb + d * 16);
    }

    // staging source addresses (pre-swizzled): instr u covers tile rows 8*(2w+u)..+7
    const int colx = (((lane & 7) ^ (lane >> 3)) << 4);    // bytes, involution pre-swizzle
    const char* kg[2];
    const char* vg[2];
#pragma unroll
    for (int u = 0; u < 2; u++) {
        int s = 2 * w + u;
        int row = 8 * s + (lane >> 3);
        kg[u] = (const char*)Kp + (((size_t)(b * SEQ + row) * DM + h * DH) * 2) + colx;
        vg[u] = (const char*)Vt + ((((size_t)(b * HEADS + h) * DH + row) * SEQ) * 2) + colx;
    }
    const int kxor = (lq & 7) << 4;

    auto stage = [&](int buf, int t) {
        int kboff_k = t * (64 * DM * 2);    // K advances 64 rows
        int kboff_v = t * 128;              // V advances 64 kv cols (bytes)
#pragma unroll
        for (int u = 0; u < 2; u++) {
            int s = 2 * w + u;
            __builtin_amdgcn_global_load_lds(
                (const __attribute__((address_space(1))) unsigned int*)(kg[u] + kboff_k),
                (__attribute__((address_space(3))) unsigned int*)(&ldsb[buf * 16384 + s * 1024 + lane * 16]), 16, 0, 0);
            __builtin_amdgcn_global_load_lds(
                (const __attribute__((address_space(1))) unsigned int*)(vg[u] + kboff_v),
                (__attribute__((address_space(3))) unsigned int*)(&ldsb[buf * 16384 + 8192 + s * 1024 + lane * 16]), 16, 0, 0);
        }
    };

    f32x16 o0 = {}, o1 = {};
    float m_run = -1e30f, l_run = 0.f;
    const int qmh0 = qq - 4 * hi;

    stage(0, 0);
    __syncthreads();

    for (int t = 0; t < nb; t++) {
        const int cur = t & 1;
        if (t + 1 < nb) stage(cur ^ 1, t + 1);

        if (t < my_nb) {
            const unsigned char* Kb = &ldsb[cur * 16384];
            const unsigned char* Vb = Kb + 8192;
            const int kb = t * 64;

            bf16x8 KA[4], KB[4], Vc[4][2];
#pragma unroll
            for (int d = 0; d < 4; d++) {
                int col = (d * 32 + hi * 16) ^ kxor;
                KA[d] = *(const bf16x8*)(Kb + lq * 128 + col);
                KB[d] = *(const bf16x8*)(Kb + (lq + 32) * 128 + col);
            }
#pragma unroll
            for (int s = 0; s < 4; s++)
#pragma unroll
                for (int dt = 0; dt < 2; dt++)
                    Vc[s][dt] = *(const bf16x8*)(Vb + (dt * 32 + lq) * 128 + ((s * 32 + hi * 16) ^ kxor));

            f32x16 sa0 = {}, sa1 = {};
#pragma unroll
            for (int d = 0; d < 4; d++) {
                sa0 = __builtin_amdgcn_mfma_f32_32x32x16_bf16(KA[d], Qf[d], sa0, 0, 0, 0);
                sa1 = __builtin_amdgcn_mfma_f32_32x32x16_bf16(KB[d], Qf[d], sa1, 0, 0, 0);
            }

            const int qmh = qmh0 - kb;
#pragma unroll
            for (int r = 0; r < 16; r++) {
                int kvl = (r & 3) + 8 * (r >> 2);
                sa0[r] = (kvl <= qmh) ? sa0[r] : -1e30f;
                sa1[r] = (kvl + 32 <= qmh) ? sa1[r] : -1e30f;
            }
            float mx[16];
#pragma unroll
            for (int r = 0; r < 16; r++) mx[r] = fmaxf(sa0[r], sa1[r]);
#pragma unroll
            for (int r = 0; r < 8; r++) mx[r] = fmaxf(mx[r], mx[r + 8]);
#pragma unroll
            for (int r = 0; r < 4; r++) mx[r] = fmaxf(mx[r], mx[r + 4]);
            mx[0] = fmaxf(mx[0], mx[2]);
            mx[1] = fmaxf(mx[1], mx[3]);
            float mloc = fmaxf(mx[0], mx[1]);
            mloc = fmaxf(mloc, __shfl_xor(mloc, 32));

            if (!__all(mloc - m_run <= THR)) {
                float m_new = fmaxf(m_run, mloc);
                float sf = __builtin_amdgcn_exp2f(m_run - m_new);
                l_run *= sf;
#pragma unroll
                for (int r = 0; r < 16; r++) { o0[r] *= sf; o1[r] *= sf; }
                m_run = m_new;
            }

            float p0v[16], p1v[16];
#pragma unroll
            for (int r = 0; r < 16; r++) {
                p0v[r] = __builtin_amdgcn_exp2f(sa0[r] - m_run);
                p1v[r] = __builtin_amdgcn_exp2f(sa1[r] - m_run);
            }
            float s4[8];
#pragma unroll
            for (int r = 0; r < 8; r++) s4[r] = (p0v[r] + p0v[r + 8]) + (p1v[r] + p1v[r + 8]);
#pragma unroll
            for (int r = 0; r < 4; r++) s4[r] += s4[r + 4];
            float ps = (s4[0] + s4[1]) + (s4[2] + s4[3]);
            ps += __shfl_xor(ps, 32);
            l_run += ps;

            unsigned c0[8], c1[8];
#pragma unroll
            for (int ii = 0; ii < 8; ii++) {
                unsigned pk;
                asm("v_cvt_pk_bf16_f32 %0, %1, %2" : "=v"(pk) : "v"(p0v[2 * ii]), "v"(p0v[2 * ii + 1]));
                c0[ii] = pk;
                asm("v_cvt_pk_bf16_f32 %0, %1, %2" : "=v"(pk) : "v"(p1v[2 * ii]), "v"(p1v[2 * ii + 1]));
                c1[ii] = pk;
            }
            bf16x8 Pb[4];
            {
                u32x2 r02 = __builtin_amdgcn_permlane32_swap(c0[0], c0[2], false, false);
                u32x2 r13 = __builtin_amdgcn_permlane32_swap(c0[1], c0[3], false, false);
                u32x2 r46 = __builtin_amdgcn_permlane32_swap(c0[4], c0[6], false, false);
                u32x2 r57 = __builtin_amdgcn_permlane32_swap(c0[5], c0[7], false, false);
                u32x4 w0 = {r02.x, r13.x, r02.y, r13.y};
                u32x4 w1 = {r46.x, r57.x, r46.y, r57.y};
                Pb[0] = __builtin_bit_cast(bf16x8, w0);
                Pb[1] = __builtin_bit_cast(bf16x8, w1);
            }
            {
                u32x2 r02 = __builtin_amdgcn_permlane32_swap(c1[0], c1[2], false, false);
                u32x2 r13 = __builtin_amdgcn_permlane32_swap(c1[1], c1[3], false, false);
                u32x2 r46 = __builtin_amdgcn_permlane32_swap(c1[4], c1[6], false, false);
                u32x2 r57 = __builtin_amdgcn_permlane32_swap(c1[5], c1[7], false, false);
                u32x4 w0 = {r02.x, r13.x, r02.y, r13.y};
                u32x4 w1 = {r46.x, r57.x, r46.y, r57.y};
                Pb[2] = __builtin_bit_cast(bf16x8, w0);
                Pb[3] = __builtin_bit_cast(bf16x8, w1);
            }

#pragma unroll
            for (int s = 0; s < 4; s++) {
                o0 = __builtin_amdgcn_mfma_f32_32x32x16_bf16(Vc[s][0], Pb[s], o0, 0, 0, 0);
                o1 = __builtin_amdgcn_mfma_f32_32x32x16_bf16(Vc[s][1], Pb[s], o1, 0, 0, 0);
            }
        }
        __syncthreads();
    }

    float inv = 1.0f / l_run;
    unsigned short* cb = Ctx + (size_t)(b * SEQ + qq) * DM + h * DH + hi * 4;
#pragma unroll
    for (int g = 0; g < 4; g++) {
        ushort4 s0, s1;
        s0.x = f2bf(o0[4 * g + 0] * inv); s0.y = f2bf(o0[4 * g + 1] * inv);
        s0.z = f2bf(o0[4 * g + 2] * inv); s0.w = f2bf(o0[4 * g + 3] * inv);
        s1.x = f2bf(o1[4 * g + 0] * inv); s1.y = f2bf(o1[4 * g + 1] * inv);
        s1.z = f2bf(o1[4 * g + 2] * inv); s1.w = f2bf(o1[4 * g + 3] * inv);
        *(ushort4*)(cb + g * 8) = s0;
        *(ushort4*)(cb + 32 + g * 8) = s1;
    }
}

extern "C" void kernel_launch(void* const* d_in, const int* in_sizes, int n_in,
                              void* d_out, int out_size, void* d_ws, size_t ws_size,
                              hipStream_t stream)
{
    const float* query = (const float*)d_in[0];
    const float* keyv  = (const float*)d_in[1];
    const float* Wq = (const float*)d_in[2];
    const float* bq = (const float*)d_in[3];
    const float* Wk = (const float*)d_in[4];
    const float* bk = (const float*)d_in[5];
    const float* Wv = (const float*)d_in[6];
    const float* bv = (const float*)d_in[7];
    const float* Wo = (const float*)d_in[8];
    const float* bo = (const float*)d_in[9];
    float* out = (float*)d_out;

    const int M = BATCH * SEQ;
    char* ws = (char*)d_ws;
    size_t off = 0;
    auto alloc = [&](size_t elems) { unsigned short* p = (unsigned short*)(ws + off); off += elems * 2; return p; };
    unsigned short* qb  = alloc((size_t)M * DM);
    unsigned short* kvb = alloc((size_t)M * DM);
    unsigned short* wqb = alloc((size_t)DM * DM);
    unsigned short* wkb = alloc((size_t)DM * DM);   // wkb and wvb MUST stay adjacent (merged KV weights)
    unsigned short* wvb = alloc((size_t)DM * DM);
    unsigned short* wob = alloc((size_t)DM * DM);
    unsigned short* Qp  = alloc((size_t)M * DM);
    unsigned short* Kp  = alloc((size_t)M * DM);
    unsigned short* Vt  = alloc((size_t)M * DM);
    unsigned short* Ctx = alloc((size_t)M * DM);

    cast_all_k<<<6144, 256, 0, stream>>>(query, keyv, Wq, Wk, Wv, Wo,
                                         qb, kvb, wqb, wkb, wvb, wob);

    gemm_nt<0><<<dim3(M / 64, 8),  256, 0, stream>>>(qb,  wqb, bq, nullptr, Qp, nullptr, M, DM, DM);
    gemm_nt<1><<<dim3(M / 64, 16), 256, 0, stream>>>(kvb, wkb, bk, bv,      Kp, Vt,      M, 2 * DM, DM);

    attn_k<<<dim3(512), 256, 0, stream>>>(Qp, Kp, Vt, Ctx);

    gemm_nt<2><<<dim3(M / 64, 8),  256, 0, stream>>>(Ctx, wob, bo, nullptr, out, nullptr, M, DM, DM);
}

// Round 9
// 119.779 us; speedup vs baseline: 1.1859x; 1.0109x over previous
//
#include <hip/hip_runtime.h>
#include <hip/hip_bf16.h>
#include <cstdint>
#include <type_traits>

#define DM 1024
#define HEADS 16
#define DH 64
#define SEQ 2048
#define BATCH 2

typedef __attribute__((ext_vector_type(8))) short bf16x8;
typedef __attribute__((ext_vector_type(4))) float f32x4;
typedef __attribute__((ext_vector_type(16))) float f32x16;
typedef __attribute__((ext_vector_type(2))) unsigned int u32x2;
typedef __attribute__((ext_vector_type(4))) unsigned int u32x4;

#define SCALE2 0.18033688011112042f   /* (1/8)*log2(e) */

#define GLOAD(dst, ptr) \
    asm volatile("global_load_dwordx4 %0, %1, off" : "=v"(dst) : "v"(ptr) : "memory")

static __device__ __forceinline__ unsigned short f2bf(float f) {
    unsigned u = __builtin_bit_cast(unsigned, f);
    u = u + 0x7fffu + ((u >> 16) & 1u);
    return (unsigned short)(u >> 16);
}

// ---------------- fused cast fp32 -> bf16, all 6 tensors in one launch ----------------
__global__ __launch_bounds__(256) void cast_all_k(
    const float* __restrict__ q, const float* __restrict__ kv,
    const float* __restrict__ wq, const float* __restrict__ wk,
    const float* __restrict__ wv, const float* __restrict__ wo,
    unsigned short* __restrict__ qb, unsigned short* __restrict__ kvb,
    unsigned short* __restrict__ wqb, unsigned short* __restrict__ wkb,
    unsigned short* __restrict__ wvb, unsigned short* __restrict__ wob)
{
    int blk = blockIdx.x;
    const float* s; unsigned short* d; int base;
    if (blk < 2048)      { s = q;  d = qb;  base = 0; }
    else if (blk < 4096) { s = kv; d = kvb; base = 2048; }
    else if (blk < 4608) { s = wq; d = wqb; base = 4096; }
    else if (blk < 5120) { s = wk; d = wkb; base = 4608; }
    else if (blk < 5632) { s = wv; d = wvb; base = 5120; }
    else                 { s = wo; d = wob; base = 5632; }
    int i = ((blk - base) * 256 + threadIdx.x) * 8;
    float4 a = *(const float4*)(s + i);
    float4 b2 = *(const float4*)(s + i + 4);
    ushort4 o0, o1;
    o0.x = f2bf(a.x);  o0.y = f2bf(a.y);  o0.z = f2bf(a.z);  o0.w = f2bf(a.w);
    o1.x = f2bf(b2.x); o1.y = f2bf(b2.y); o1.z = f2bf(b2.z); o1.w = f2bf(b2.w);
    *(ushort4*)(d + i) = o0;
    *(ushort4*)(d + i + 4) = o1;
}

// ---------------- NT GEMM: C[m][n] = sum_k A[m][k]*B[n][k] + bias[n] ----------------
template<int EPI>
__global__ __launch_bounds__(256) void gemm_nt(
    const unsigned short* __restrict__ A,
    const unsigned short* __restrict__ Bw,
    const float* __restrict__ biasA,
    const float* __restrict__ biasB,
    void* __restrict__ out0,
    void* __restrict__ out1,
    int M, int N, int K)
{
    constexpr int BK = 64;
    __shared__ alignas(16) unsigned short As[64 * BK];
    __shared__ alignas(16) unsigned short Bs[128 * BK];

    const int t = threadIdx.x;
    const int lane = t & 63;
    const int w = t >> 6;
    const int wn = w * 32;
    const int lr = lane & 15, lg = lane >> 4;
    const int m0 = blockIdx.x * 64, n0 = blockIdx.y * 128;

    f32x4 acc[4][2] = {};

    const int srow = t >> 3;
    const int schunk = t & 7;

    for (int kt = 0; kt < K; kt += BK) {
#pragma unroll
        for (int c = 0; c < 2; c++) {
            int row = srow + c * 32;
            int gc = schunk ^ (row & 7);
            __builtin_amdgcn_global_load_lds(
                (const __attribute__((address_space(1))) unsigned int*)(A + (size_t)(m0 + row) * K + kt + gc * 8),
                (__attribute__((address_space(3))) unsigned int*)(&As[row * BK + schunk * 8]), 16, 0, 0);
        }
#pragma unroll
        for (int c = 0; c < 4; c++) {
            int row = srow + c * 32;
            int gc = schunk ^ (row & 7);
            __builtin_amdgcn_global_load_lds(
                (const __attribute__((address_space(1))) unsigned int*)(Bw + (size_t)(n0 + row) * K + kt + gc * 8),
                (__attribute__((address_space(3))) unsigned int*)(&Bs[row * BK + schunk * 8]), 16, 0, 0);
        }
        __syncthreads();
#pragma unroll
        for (int kk = 0; kk < 2; kk++) {
            bf16x8 af[4], bfr[2];
#pragma unroll
            for (int i = 0; i < 4; i++)
                af[i] = *(const bf16x8*)(&As[(i * 16 + lr) * BK + (((kk * 4 + lg) ^ (lr & 7))) * 8]);
#pragma unroll
            for (int jj = 0; jj < 2; jj++)
                bfr[jj] = *(const bf16x8*)(&Bs[(wn + jj * 16 + lr) * BK + (((kk * 4 + lg) ^ (lr & 7))) * 8]);
#pragma unroll
            for (int i = 0; i < 4; i++)
#pragma unroll
                for (int jj = 0; jj < 2; jj++)
                    acc[i][jj] = __builtin_amdgcn_mfma_f32_16x16x32_bf16(af[i], bfr[jj], acc[i][jj], 0, 0, 0);
        }
        __syncthreads();
    }

    if constexpr (EPI == 0) {
        unsigned short* C = (unsigned short*)out0;
#pragma unroll
        for (int i = 0; i < 4; i++) {
            int rbase = m0 + i * 16 + lg * 4;
#pragma unroll
            for (int jj = 0; jj < 2; jj++) {
                int col = n0 + wn + jj * 16 + lr;
                float bv = biasA[col];
#pragma unroll
                for (int r = 0; r < 4; r++)
                    C[(size_t)(rbase + r) * 1024 + col] = f2bf((acc[i][jj][r] + bv) * SCALE2);
            }
        }
    } else if constexpr (EPI == 1) {
        if (n0 < 1024) {
            unsigned short* C = (unsigned short*)out0;
#pragma unroll
            for (int i = 0; i < 4; i++) {
                int rbase = m0 + i * 16 + lg * 4;
#pragma unroll
                for (int jj = 0; jj < 2; jj++) {
                    int col = n0 + wn + jj * 16 + lr;
                    float bv = biasA[col];
#pragma unroll
                    for (int r = 0; r < 4; r++)
                        C[(size_t)(rbase + r) * 1024 + col] = f2bf(acc[i][jj][r] + bv);
                }
            }
        } else {
            unsigned short* C = (unsigned short*)out1;
            int bidx = m0 >> 11;
#pragma unroll
            for (int i = 0; i < 4; i++) {
                int s0 = (m0 & 2047) + i * 16 + lg * 4;
#pragma unroll
                for (int jj = 0; jj < 2; jj++) {
                    int nv = n0 - 1024 + wn + jj * 16 + lr;
                    float bv = biasB[nv];
                    int hh = nv >> 6, dd = nv & 63;
                    ushort4 st;
                    st.x = f2bf(acc[i][jj][0] + bv);
                    st.y = f2bf(acc[i][jj][1] + bv);
                    st.z = f2bf(acc[i][jj][2] + bv);
                    st.w = f2bf(acc[i][jj][3] + bv);
                    *(ushort4*)(C + ((size_t)((bidx * HEADS + hh) * DH + dd)) * SEQ + s0) = st;
                }
            }
        }
    } else {
        float* C = (float*)out0;
#pragma unroll
        for (int i = 0; i < 4; i++) {
            int rbase = m0 + i * 16 + lg * 4;
#pragma unroll
            for (int jj = 0; jj < 2; jj++) {
                int col = n0 + wn + jj * 16 + lr;
                float bv = biasA[col];
#pragma unroll
                for (int r = 0; r < 4; r++)
                    C[(size_t)(rbase + r) * 1024 + col] = acc[i][jj][r] + bv;
            }
        }
    }
}

// ---------------- causal flash attention: LDS-staged K/V, counted-vmcnt pipeline ----------------
// Qp (pre-scaled), Kp: bf16 [B][S][1024]; Vt: bf16 [B][H][64][S]; Ctx: bf16 [B][S][1024]
// Grid 512 = 32 bh x 16 q-chunks(128 rows), paired (x, x+256) for constant work.
// Per iter: issue stage(t+1) [4 loads/wave]; s_waitcnt vmcnt(4) => stage(t) landed,
// stage(t+1) in flight; s_barrier; ds_read+compute; s_barrier. Tail: vmcnt(0).
__global__ __launch_bounds__(256, 2) void attn_k(
    const unsigned short* __restrict__ Qp,
    const unsigned short* __restrict__ Kp,
    const unsigned short* __restrict__ Vt,
    unsigned short* __restrict__ Ctx)
{
    __shared__ alignas(16) unsigned char ldsb[2 * 16384];   // [buf][K 8KB | V 8KB]

    const int lane = threadIdx.x & 63;
    const int w = threadIdx.x >> 6;          // 0..3
    const int x = blockIdx.x;
    const int bh = x & 31;
    const int i16 = x >> 5;                  // 0..15
    const int c = (i16 < 8) ? (2 * i16) : (31 - 2 * i16);   // pair-sum = 15
    const int b = bh >> 4, h = bh & 15;
    const int q0 = c * 128;
    const int lq = lane & 31;
    const int hi = lane >> 5;
    const int qq = q0 + w * 32 + lq;
    const int nb = 2 * c + 2;                              // block iterations
    const int my_nb = (q0 + 32 * w + 95) >> 6;             // this wave's compute iterations
    constexpr float THR = 11.5f;

    // Q via asm loads + full drain: compiler's VMEM FIFO then tracks ONLY staging loads
    bf16x8 Qf[4];
    {
        u32x4 qtmp[4];
        const unsigned short* qb = Qp + (size_t)(b * SEQ + qq) * DM + h * DH + hi * 8;
#pragma unroll
        for (int d = 0; d < 4; d++) GLOAD(qtmp[d], qb + d * 16);
        asm volatile("s_waitcnt vmcnt(0)" ::: "memory");
        __builtin_amdgcn_sched_barrier(0);
#pragma unroll
        for (int d = 0; d < 4; d++) Qf[d] = __builtin_bit_cast(bf16x8, qtmp[d]);
    }

    // staging source addresses (pre-swizzled involution, rule 21)
    const int colx = (((lane & 7) ^ (lane >> 3)) << 4);
    const char* kg[2];
    const char* vg[2];
#pragma unroll
    for (int u = 0; u < 2; u++) {
        int s = 2 * w + u;
        int row = 8 * s + (lane >> 3);
        kg[u] = (const char*)Kp + (((size_t)(b * SEQ + row) * DM + h * DH) * 2) + colx;
        vg[u] = (const char*)Vt + ((((size_t)(b * HEADS + h) * DH + row) * SEQ) * 2) + colx;
    }
    const int kxor = (lq & 7) << 4;

    auto stage = [&](int buf, int t) {
        int kboff_k = t * (64 * DM * 2);    // K advances 64 rows
        int kboff_v = t * 128;              // V advances 64 kv cols (bytes)
#pragma unroll
        for (int u = 0; u < 2; u++) {
            int s = 2 * w + u;
            __builtin_amdgcn_global_load_lds(
                (const __attribute__((address_space(1))) unsigned int*)(kg[u] + kboff_k),
                (__attribute__((address_space(3))) unsigned int*)(&ldsb[buf * 16384 + s * 1024 + lane * 16]), 16, 0, 0);
            __builtin_amdgcn_global_load_lds(
                (const __attribute__((address_space(1))) unsigned int*)(vg[u] + kboff_v),
                (__attribute__((address_space(3))) unsigned int*)(&ldsb[buf * 16384 + 8192 + s * 1024 + lane * 16]), 16, 0, 0);
        }
    };

    f32x16 o0 = {}, o1 = {};
    float m_run = -1e30f, l_run = 0.f;
    const int qmh0 = qq - 4 * hi;

    stage(0, 0);   // prologue: 4 loads/wave in flight

    for (int t = 0; t < nb; t++) {
        const int cur = t & 1;
        // issue next-tile prefetch, then counted wait: stage(t) complete, stage(t+1) in flight
        if (t + 1 < nb) {
            stage(cur ^ 1, t + 1);
            asm volatile("s_waitcnt vmcnt(4)" ::: "memory");
        } else {
            asm volatile("s_waitcnt vmcnt(0)" ::: "memory");
        }
        __builtin_amdgcn_sched_barrier(0);
        __builtin_amdgcn_s_barrier();      // all waves' stage(t) landed -> buf cur valid

        if (t < my_nb) {
            const unsigned char* Kb = &ldsb[cur * 16384];
            const unsigned char* Vb = Kb + 8192;
            const int kb = t * 64;

            bf16x8 KA[4], KB[4], Vc[4][2];
#pragma unroll
            for (int d = 0; d < 4; d++) {
                int col = (d * 32 + hi * 16) ^ kxor;
                KA[d] = *(const bf16x8*)(Kb + lq * 128 + col);
                KB[d] = *(const bf16x8*)(Kb + (lq + 32) * 128 + col);
            }
#pragma unroll
            for (int s = 0; s < 4; s++)
#pragma unroll
                for (int dt = 0; dt < 2; dt++)
                    Vc[s][dt] = *(const bf16x8*)(Vb + (dt * 32 + lq) * 128 + ((s * 32 + hi * 16) ^ kxor));

            f32x16 sa0 = {}, sa1 = {};
            __builtin_amdgcn_s_setprio(1);
#pragma unroll
            for (int d = 0; d < 4; d++) {
                sa0 = __builtin_amdgcn_mfma_f32_32x32x16_bf16(KA[d], Qf[d], sa0, 0, 0, 0);
                sa1 = __builtin_amdgcn_mfma_f32_32x32x16_bf16(KB[d], Qf[d], sa1, 0, 0, 0);
            }
            __builtin_amdgcn_s_setprio(0);

            const int qmh = qmh0 - kb;
#pragma unroll
            for (int r = 0; r < 16; r++) {
                int kvl = (r & 3) + 8 * (r >> 2);
                sa0[r] = (kvl <= qmh) ? sa0[r] : -1e30f;
                sa1[r] = (kvl + 32 <= qmh) ? sa1[r] : -1e30f;
            }
            float mx[16];
#pragma unroll
            for (int r = 0; r < 16; r++) mx[r] = fmaxf(sa0[r], sa1[r]);
#pragma unroll
            for (int r = 0; r < 8; r++) mx[r] = fmaxf(mx[r], mx[r + 8]);
#pragma unroll
            for (int r = 0; r < 4; r++) mx[r] = fmaxf(mx[r], mx[r + 4]);
            mx[0] = fmaxf(mx[0], mx[2]);
            mx[1] = fmaxf(mx[1], mx[3]);
            float mloc = fmaxf(mx[0], mx[1]);
            mloc = fmaxf(mloc, __shfl_xor(mloc, 32));

            if (!__all(mloc - m_run <= THR)) {
                float m_new = fmaxf(m_run, mloc);
                float sf = __builtin_amdgcn_exp2f(m_run - m_new);
                l_run *= sf;
#pragma unroll
                for (int r = 0; r < 16; r++) { o0[r] *= sf; o1[r] *= sf; }
                m_run = m_new;
            }

            float p0v[16], p1v[16];
#pragma unroll
            for (int r = 0; r < 16; r++) {
                p0v[r] = __builtin_amdgcn_exp2f(sa0[r] - m_run);
                p1v[r] = __builtin_amdgcn_exp2f(sa1[r] - m_run);
            }
            float s4[8];
#pragma unroll
            for (int r = 0; r < 8; r++) s4[r] = (p0v[r] + p0v[r + 8]) + (p1v[r] + p1v[r + 8]);
#pragma unroll
            for (int r = 0; r < 4; r++) s4[r] += s4[r + 4];
            float ps = (s4[0] + s4[1]) + (s4[2] + s4[3]);
            ps += __shfl_xor(ps, 32);
            l_run += ps;

            unsigned c0[8], c1[8];
#pragma unroll
            for (int ii = 0; ii < 8; ii++) {
                unsigned pk;
                asm("v_cvt_pk_bf16_f32 %0, %1, %2" : "=v"(pk) : "v"(p0v[2 * ii]), "v"(p0v[2 * ii + 1]));
                c0[ii] = pk;
                asm("v_cvt_pk_bf16_f32 %0, %1, %2" : "=v"(pk) : "v"(p1v[2 * ii]), "v"(p1v[2 * ii + 1]));
                c1[ii] = pk;
            }
            bf16x8 Pb[4];
            {
                u32x2 r02 = __builtin_amdgcn_permlane32_swap(c0[0], c0[2], false, false);
                u32x2 r13 = __builtin_amdgcn_permlane32_swap(c0[1], c0[3], false, false);
                u32x2 r46 = __builtin_amdgcn_permlane32_swap(c0[4], c0[6], false, false);
                u32x2 r57 = __builtin_amdgcn_permlane32_swap(c0[5], c0[7], false, false);
                u32x4 w0 = {r02.x, r13.x, r02.y, r13.y};
                u32x4 w1 = {r46.x, r57.x, r46.y, r57.y};
                Pb[0] = __builtin_bit_cast(bf16x8, w0);
                Pb[1] = __builtin_bit_cast(bf16x8, w1);
            }
            {
                u32x2 r02 = __builtin_amdgcn_permlane32_swap(c1[0], c1[2], false, false);
                u32x2 r13 = __builtin_amdgcn_permlane32_swap(c1[1], c1[3], false, false);
                u32x2 r46 = __builtin_amdgcn_permlane32_swap(c1[4], c1[6], false, false);
                u32x2 r57 = __builtin_amdgcn_permlane32_swap(c1[5], c1[7], false, false);
                u32x4 w0 = {r02.x, r13.x, r02.y, r13.y};
                u32x4 w1 = {r46.x, r57.x, r46.y, r57.y};
                Pb[2] = __builtin_bit_cast(bf16x8, w0);
                Pb[3] = __builtin_bit_cast(bf16x8, w1);
            }

            __builtin_amdgcn_s_setprio(1);
#pragma unroll
            for (int s = 0; s < 4; s++) {
                o0 = __builtin_amdgcn_mfma_f32_32x32x16_bf16(Vc[s][0], Pb[s], o0, 0, 0, 0);
                o1 = __builtin_amdgcn_mfma_f32_32x32x16_bf16(Vc[s][1], Pb[s], o1, 0, 0, 0);
            }
            __builtin_amdgcn_s_setprio(0);
        }
        __builtin_amdgcn_s_barrier();      // all reads of buf cur done before next overwrite
    }

    float inv = 1.0f / l_run;
    unsigned short* cb = Ctx + (size_t)(b * SEQ + qq) * DM + h * DH + hi * 4;
#pragma unroll
    for (int g = 0; g < 4; g++) {
        ushort4 s0, s1;
        s0.x = f2bf(o0[4 * g + 0] * inv); s0.y = f2bf(o0[4 * g + 1] * inv);
        s0.z = f2bf(o0[4 * g + 2] * inv); s0.w = f2bf(o0[4 * g + 3] * inv);
        s1.x = f2bf(o1[4 * g + 0] * inv); s1.y = f2bf(o1[4 * g + 1] * inv);
        s1.z = f2bf(o1[4 * g + 2] * inv); s1.w = f2bf(o1[4 * g + 3] * inv);
        *(ushort4*)(cb + g * 8) = s0;
        *(ushort4*)(cb + 32 + g * 8) = s1;
    }
}

extern "C" void kernel_launch(void* const* d_in, const int* in_sizes, int n_in,
                              void* d_out, int out_size, void* d_ws, size_t ws_size,
                              hipStream_t stream)
{
    const float* query = (const float*)d_in[0];
    const float* keyv  = (const float*)d_in[1];
    const float* Wq = (const float*)d_in[2];
    const float* bq = (const float*)d_in[3];
    const float* Wk = (const float*)d_in[4];
    const float* bk = (const float*)d_in[5];
    const float* Wv = (const float*)d_in[6];
    const float* bv = (const float*)d_in[7];
    const float* Wo = (const float*)d_in[8];
    const float* bo = (const float*)d_in[9];
    float* out = (float*)d_out;

    const int M = BATCH * SEQ;
    char* ws = (char*)d_ws;
    size_t off = 0;
    auto alloc = [&](size_t elems) { unsigned short* p = (unsigned short*)(ws + off); off += elems * 2; return p; };
    unsigned short* qb  = alloc((size_t)M * DM);
    unsigned short* kvb = alloc((size_t)M * DM);
    unsigned short* wqb = alloc((size_t)DM * DM);
    unsigned short* wkb = alloc((size_t)DM * DM);   // wkb and wvb MUST stay adjacent (merged KV weights)
    unsigned short* wvb = alloc((size_t)DM * DM);
    unsigned short* wob = alloc((size_t)DM * DM);
    unsigned short* Qp  = alloc((size_t)M * DM);
    unsigned short* Kp  = alloc((size_t)M * DM);
    unsigned short* Vt  = alloc((size_t)M * DM);
    unsigned short* Ctx = alloc((size_t)M * DM);

    cast_all_k<<<6144, 256, 0, stream>>>(query, keyv, Wq, Wk, Wv, Wo,
                                         qb, kvb, wqb, wkb, wvb, wob);

    gemm_nt<0><<<dim3(M / 64, 8),  256, 0, stream>>>(qb,  wqb, bq, nullptr, Qp, nullptr, M, DM, DM);
    gemm_nt<1><<<dim3(M / 64, 16), 256, 0, stream>>>(kvb, wkb, bk, bv,      Kp, Vt,      M, 2 * DM, DM);

    attn_k<<<dim3(512), 256, 0, stream>>>(Qp, Kp, Vt, Ctx);

    gemm_nt<2><<<dim3(M / 64, 8),  256, 0, stream>>>(Ctx, wob, bo, nullptr, out, nullptr, M, DM, DM);
}